// Round 7
// baseline (620.616 us; speedup 1.0000x reference)
//
#include <hip/hip_runtime.h>

// RGCN: 2-layer, R=4, N=100000, E=500000/rel, 128->128->64.
// Round 7: XCD-sharded degree histogram with L2-local (workgroup-scope)
// atomics; packed src/dst counters; slot=(xcd,rank); grid-fused prep and
// fill||gemm; bf16 Y; MFMA bf16-split GEMM; CSR gather.

constexpr int Nn  = 100000;
constexpr int Rr  = 4;
constexpr int Ee  = 500000;
constexpr int RE  = Rr * Ee;
constexpr int TOT = Rr * Nn;
constexpr int NP  = 100096;            // Nn padded to 128 rows
constexpr int NPB = NP / 128;          // 782 row-blocks
constexpr int NB1 = 1024;
constexpr int CH  = (TOT + NB1 - 1) / NB1;
constexpr int NXCD = 8;

// fused-prep grid decode
constexpr int CB   = (RE + 255) / 256;              // 7813 count blocks
constexpr int XB   = (NP * 128 / 8 + 255) / 256;    // 6256 convx blocks
constexpr int WB   = 384;                           // convw blocks (exact)
constexpr int PAIR = 2 * XB;                        // interleaved region
constexpr int PREP_GRID = PAIR + (CB - XB) + WB + 1;

// fused fill+gemm grid decode
constexpr int FB    = (RE / 4 + 255) / 256;         // 1954 fill blocks
constexpr int GB    = 4 * NPB;                      // 3128 gemm blocks
constexpr int PAIR2 = 2 * FB;
constexpr int FG_GRID = PAIR2 + (GB - FB);

typedef short bf16x8 __attribute__((ext_vector_type(8)));
typedef float f32x4  __attribute__((ext_vector_type(4)));

__device__ __forceinline__ unsigned short f2bf(float f) {
    unsigned u = __builtin_bit_cast(unsigned, f);
    u = u + 0x7FFFu + ((u >> 16) & 1u);          // round-to-nearest-even
    return (unsigned short)(u >> 16);
}
__device__ __forceinline__ float bf2f(unsigned short h) {
    unsigned u = ((unsigned)h) << 16;
    return __builtin_bit_cast(float, u);
}
__device__ __forceinline__ float bfbits_lo(unsigned p) {
    return __builtin_bit_cast(float, p << 16);
}
__device__ __forceinline__ float bfbits_hi(unsigned p) {
    return __builtin_bit_cast(float, p & 0xFFFF0000u);
}
__device__ __forceinline__ unsigned xcc_id() {
    unsigned x;
    asm volatile("s_getreg_b32 %0, hwreg(HW_REG_XCC_ID, 0, 4)" : "=s"(x));
    return x & (NXCD - 1);
}

// ---------------- role bodies ----------------
// degS[x][i]: lo16 = out-degree(src), hi16 = in-degree(dst), shard x = XCD.
// L2-local atomics: only blocks on XCD x touch shard x.
__device__ __forceinline__ void count_body(int sub, int tid,
    const int* __restrict__ src, const int* __restrict__ dst,
    unsigned* __restrict__ degS, unsigned* __restrict__ slot)
{
    int e = sub * 256 + tid;
    if (e >= RE) return;
    int r = (unsigned)e / (unsigned)Ee;
    int base = r * Nn;
    unsigned x = xcc_id();
    unsigned* shard = degS + (size_t)x * TOT;
    __hip_atomic_fetch_add(&shard[base + src[e]], 1u,
                           __ATOMIC_RELAXED, __HIP_MEMORY_SCOPE_WORKGROUP);
    unsigned old = __hip_atomic_fetch_add(&shard[base + dst[e]], 0x10000u,
                                          __ATOMIC_RELAXED, __HIP_MEMORY_SCOPE_WORKGROUP);
    slot[e] = (old >> 16) | (x << 27);           // rank within (r,dst,xcd)
}

__device__ __forceinline__ void convx_body(int sub, int tid,
    const float* __restrict__ X, short* __restrict__ Xh, short* __restrict__ Xl)
{
    size_t base = ((size_t)sub * 256 + tid) * 8;
    if (base >= (size_t)NP * 128) return;
    bf16x8 hv, lv;
    #pragma unroll
    for (int i = 0; i < 8; ++i) { hv[i] = 0; lv[i] = 0; }
    if (base < (size_t)Nn * 128) {
        float4 a = *reinterpret_cast<const float4*>(X + base);
        float4 b = *reinterpret_cast<const float4*>(X + base + 4);
        float f[8] = {a.x, a.y, a.z, a.w, b.x, b.y, b.z, b.w};
        #pragma unroll
        for (int i = 0; i < 8; ++i) {
            unsigned short h = f2bf(f[i]);
            hv[i] = (short)h;
            lv[i] = (short)f2bf(f[i] - bf2f(h));
        }
    }
    *reinterpret_cast<bf16x8*>(Xh + base) = hv;
    *reinterpret_cast<bf16x8*>(Xl + base) = lv;
}

__device__ __forceinline__ void convw_body(int sub, int tid,
    const float* __restrict__ W1, const float* __restrict__ W2,
    short* __restrict__ w1h, short* __restrict__ w1l,
    short* __restrict__ w2h, short* __restrict__ w2l)
{
    int gid = sub * 256 + tid;
    if (gid < 4 * 128 * 128) {
        int r = gid >> 14, rem = gid & 16383, n = rem >> 7, k = rem & 127;
        float v = W1[(r << 14) + k * 128 + n];
        unsigned short h = f2bf(v);
        unsigned short l = f2bf(v - bf2f(h));
        w1h[(r << 14) + n * 128 + k] = (short)h;
        w1l[(r << 14) + n * 128 + k] = (short)l;
    } else {
        int g2 = gid - 65536;
        if (g2 >= 4 * 64 * 128) return;
        int r = g2 >> 13, rem = g2 & 8191, n = rem >> 7, k = rem & 127;
        float v = W2[(r << 13) + k * 64 + n];
        unsigned short h = f2bf(v);
        unsigned short l = f2bf(v - bf2f(h));
        w2h[(r << 13) + n * 128 + k] = (short)h;
        w2l[(r << 13) + n * 128 + k] = (short)l;
    }
}

__device__ __forceinline__ void bsum_body(int tid,
    const float* __restrict__ b1, const float* __restrict__ b2,
    float* __restrict__ bs1, float* __restrict__ bs2)
{
    if (tid < 128) bs1[tid] = b1[tid] + b1[128 + tid] + b1[256 + tid] + b1[384 + tid];
    if (tid < 64)  bs2[tid] = b2[tid] + b2[64 + tid] + b2[128 + tid] + b2[192 + tid];
}

// ---------------- fused prep: count || convx || convw || bsum ----------------
__global__ __launch_bounds__(256)
void prep_kernel(const int* __restrict__ src, const int* __restrict__ dst,
                 unsigned* __restrict__ degS, unsigned* __restrict__ slot,
                 const float* __restrict__ X, short* __restrict__ Xh, short* __restrict__ Xl,
                 const float* __restrict__ W1, const float* __restrict__ W2,
                 short* __restrict__ w1h, short* __restrict__ w1l,
                 short* __restrict__ w2h, short* __restrict__ w2l,
                 const float* __restrict__ b1, const float* __restrict__ b2,
                 float* __restrict__ bs1, float* __restrict__ bs2)
{
    int bid = blockIdx.x, tid = threadIdx.x;
    if (bid < PAIR) {
        if (bid & 1) convx_body(bid >> 1, tid, X, Xh, Xl);
        else         count_body(bid >> 1, tid, src, dst, degS, slot);
    } else {
        int t = bid - PAIR;
        if (t < CB - XB)      count_body(XB + t, tid, src, dst, degS, slot);
        else if ((t -= CB - XB) < WB) convw_body(t, tid, W1, W2, w1h, w1l, w2h, w2l);
        else                  bsum_body(tid, b1, b2, bs1, bs2);
    }
}

// reduce shards -> norms; overwrite shards with per-XCD exclusive dst-prefix;
// emit summed in-degree for the scan.
__global__ __launch_bounds__(256)
void norms_kernel(unsigned* __restrict__ degS, float* __restrict__ nrm,
                  uint2* __restrict__ rpnd, unsigned* __restrict__ dsum)
{
    int gid = blockIdx.x * 256 + threadIdx.x;
    if (gid >= TOT) return;
    unsigned s = 0, run = 0;
    #pragma unroll
    for (int x = 0; x < NXCD; ++x) {
        unsigned v = degS[(size_t)x * TOT + gid];
        s += v & 0xFFFFu;
        degS[(size_t)x * TOT + gid] = run;       // exclusive prefix (dst side)
        run += v >> 16;
    }
    nrm[gid] = rsqrtf((float)(s > 0u ? s : 1u));
    rpnd[gid].y = __builtin_bit_cast(unsigned, rsqrtf((float)(run > 0u ? run : 1u)));
    dsum[gid] = run;
}

__global__ __launch_bounds__(256)
void scan1_kernel(const unsigned* __restrict__ dsum, unsigned* __restrict__ partial)
{
    __shared__ unsigned s[256];
    int b = blockIdx.x, t = threadIdx.x;
    int start = b * CH;
    int n = TOT - start; if (n > CH) n = CH;
    unsigned sum = 0;
    for (int i = t; i < n; i += 256) sum += dsum[start + i];
    s[t] = sum; __syncthreads();
    for (int d = 128; d > 0; d >>= 1) {
        if (t < d) s[t] += s[t + d];
        __syncthreads();
    }
    if (t == 0) partial[b] = s[0];
}

__global__ __launch_bounds__(1024)
void scan2_kernel(unsigned* __restrict__ partial, unsigned* __restrict__ rowptr)
{
    __shared__ unsigned s[NB1];
    int t = threadIdx.x;
    unsigned orig = partial[t];
    s[t] = orig; __syncthreads();
    for (int d = 1; d < NB1; d <<= 1) {
        unsigned v = (t >= d) ? s[t - d] : 0u;
        __syncthreads();
        s[t] += v;
        __syncthreads();
    }
    partial[t] = s[t] - orig;
    if (t == 0) rowptr[TOT] = (unsigned)RE;
}

__global__ __launch_bounds__(256)
void scan3_kernel(const unsigned* __restrict__ dsum, const unsigned* __restrict__ base,
                  unsigned* __restrict__ rowptr, uint2* __restrict__ rpnd)
{
    __shared__ unsigned s[CH];
    int b = blockIdx.x, t = threadIdx.x;
    int start = b * CH;
    int n = TOT - start; if (n > CH) n = CH;
    if (n <= 0) return;
    for (int i = t; i < n; i += 256) s[i] = dsum[start + i];
    __syncthreads();
    if (t == 0) {
        unsigned run = base[b];
        for (int i = 0; i < n; ++i) { unsigned v = s[i]; s[i] = run; run += v; }
    }
    __syncthreads();
    for (int i = t; i < n; i += 256) {
        unsigned v = s[i];
        rowptr[start + i] = v;
        rpnd[start + i].x = v;
    }
}

// ---------------- GEMM body (MFMA, bf16 hi/lo split, bf16 out) ----------------
template<int BN>
__device__ __forceinline__ void gemm_body(
    const short* __restrict__ Xh, const short* __restrict__ Xl,
    const short* __restrict__ WhT_, const short* __restrict__ WlT_,
    short* __restrict__ Y_, int CW, int rowblk, int rel)
{
    constexpr int BM = 128, BKp = 40;            // 32 k + 8 pad
    constexpr int MFR = (BN == 128) ? 4 : 2;
    constexpr int NFR = 4;
    const short* WhT = WhT_ + (size_t)rel * (BN * 128);
    const short* WlT = WlT_ + (size_t)rel * (BN * 128);
    short* Y = Y_ + (size_t)rel * BN;

    __shared__ __align__(16) short Ah[BM * BKp], Al[BM * BKp];
    __shared__ __align__(16) short Bh[BN * BKp], Bl[BN * BKp];

    const int tid = threadIdx.x;
    const int lane = tid & 63, wid = tid >> 6;
    const int lr = lane & 15, lg = lane >> 4;
    const int wm0 = (BN == 128) ? (wid >> 1) * 64 : wid * 32;
    const int wn0 = (BN == 128) ? (wid & 1) * 64 : 0;
    const int row0 = rowblk * BM;

    f32x4 acc[MFR][NFR];
    #pragma unroll
    for (int m = 0; m < MFR; ++m)
        #pragma unroll
        for (int n = 0; n < NFR; ++n)
            #pragma unroll
            for (int j = 0; j < 4; ++j) acc[m][n][j] = 0.f;

    const int sr = tid >> 1;
    const int sko = (tid & 1) * 16;

    for (int ks = 0; ks < 4; ++ks) {
        size_t ga = (size_t)(row0 + sr) * 128 + ks * 32 + sko;
        *reinterpret_cast<bf16x8*>(&Ah[sr * BKp + sko])     = *reinterpret_cast<const bf16x8*>(&Xh[ga]);
        *reinterpret_cast<bf16x8*>(&Ah[sr * BKp + sko + 8]) = *reinterpret_cast<const bf16x8*>(&Xh[ga + 8]);
        *reinterpret_cast<bf16x8*>(&Al[sr * BKp + sko])     = *reinterpret_cast<const bf16x8*>(&Xl[ga]);
        *reinterpret_cast<bf16x8*>(&Al[sr * BKp + sko + 8]) = *reinterpret_cast<const bf16x8*>(&Xl[ga + 8]);
        if (BN == 128 || tid < 128) {
            size_t gb = (size_t)sr * 128 + ks * 32 + sko;
            *reinterpret_cast<bf16x8*>(&Bh[sr * BKp + sko])     = *reinterpret_cast<const bf16x8*>(&WhT[gb]);
            *reinterpret_cast<bf16x8*>(&Bh[sr * BKp + sko + 8]) = *reinterpret_cast<const bf16x8*>(&WhT[gb + 8]);
            *reinterpret_cast<bf16x8*>(&Bl[sr * BKp + sko])     = *reinterpret_cast<const bf16x8*>(&WlT[gb]);
            *reinterpret_cast<bf16x8*>(&Bl[sr * BKp + sko + 8]) = *reinterpret_cast<const bf16x8*>(&WlT[gb + 8]);
        }
        __syncthreads();

        bf16x8 bh[NFR], bl[NFR];
        #pragma unroll
        for (int n = 0; n < NFR; ++n) {
            bh[n] = *reinterpret_cast<const bf16x8*>(&Bh[(wn0 + n * 16 + lr) * BKp + lg * 8]);
            bl[n] = *reinterpret_cast<const bf16x8*>(&Bl[(wn0 + n * 16 + lr) * BKp + lg * 8]);
        }
        #pragma unroll
        for (int m = 0; m < MFR; ++m) {
            bf16x8 ah = *reinterpret_cast<const bf16x8*>(&Ah[(wm0 + m * 16 + lr) * BKp + lg * 8]);
            bf16x8 al = *reinterpret_cast<const bf16x8*>(&Al[(wm0 + m * 16 + lr) * BKp + lg * 8]);
            #pragma unroll
            for (int n = 0; n < NFR; ++n) {
                acc[m][n] = __builtin_amdgcn_mfma_f32_16x16x32_bf16(ah, bh[n], acc[m][n], 0, 0, 0);
                acc[m][n] = __builtin_amdgcn_mfma_f32_16x16x32_bf16(ah, bl[n], acc[m][n], 0, 0, 0);
                acc[m][n] = __builtin_amdgcn_mfma_f32_16x16x32_bf16(al, bh[n], acc[m][n], 0, 0, 0);
            }
        }
        __syncthreads();
    }

    // C/D layout: col=lane&15, row=(lane>>4)*4+j  [m89]
    #pragma unroll
    for (int m = 0; m < MFR; ++m)
        #pragma unroll
        for (int n = 0; n < NFR; ++n) {
            int col = wn0 + n * 16 + lr;
            int rb = row0 + wm0 + m * 16 + lg * 4;
            #pragma unroll
            for (int j = 0; j < 4; ++j)
                Y[(size_t)(rb + j) * CW + col] = (short)f2bf(acc[m][n][j]);
        }
}

// atomic-free CSR fill body: pos = rowptr + xcd_prefix + rank (4 edges/thread)
__device__ __forceinline__ void fill_body(int sub, int tid,
    const int* __restrict__ src, const int* __restrict__ dst,
    const unsigned* __restrict__ slot, const unsigned* __restrict__ degS,
    const uint2* __restrict__ rpnd, const float* __restrict__ nrm,
    int2* __restrict__ csrw)
{
    int e0 = (sub * 256 + tid) * 4;
    if (e0 >= RE) return;
    int r = (unsigned)e0 / (unsigned)Ee;
    int base = r * Nn;
    int4 s4 = *reinterpret_cast<const int4*>(src + e0);
    int4 d4 = *reinterpret_cast<const int4*>(dst + e0);
    uint4 sl = *reinterpret_cast<const uint4*>(slot + e0);
    #pragma unroll
    for (int i = 0; i < 4; ++i) {
        int s = (i == 0) ? s4.x : (i == 1) ? s4.y : (i == 2) ? s4.z : s4.w;
        int d = (i == 0) ? d4.x : (i == 1) ? d4.y : (i == 2) ? d4.z : d4.w;
        unsigned p = (i == 0) ? sl.x : (i == 1) ? sl.y : (i == 2) ? sl.z : sl.w;
        unsigned x  = p >> 27;
        unsigned rk = p & 0x07FFFFFFu;
        uint2 rn = rpnd[base + d];
        unsigned xo = degS[(size_t)x * TOT + base + d];
        float w = nrm[base + s] * __builtin_bit_cast(float, rn.y);
        int2 v; v.x = s; v.y = __builtin_bit_cast(int, w);
        csrw[rn.x + xo + rk] = v;
    }
}

// ---------------- fused: fill_csr || gemm128 (all 4 relations) ----------------
__global__ __launch_bounds__(256)
void fill_gemm_kernel(const int* __restrict__ src, const int* __restrict__ dst,
                      const unsigned* __restrict__ slot, const unsigned* __restrict__ degS,
                      const uint2* __restrict__ rpnd, const float* __restrict__ nrm,
                      int2* __restrict__ csrw,
                      const short* __restrict__ Xh, const short* __restrict__ Xl,
                      const short* __restrict__ w1h, const short* __restrict__ w1l,
                      short* __restrict__ Y)
{
    int bid = blockIdx.x, tid = threadIdx.x;
    int role, sub;
    if (bid < PAIR2) { role = bid & 1; sub = bid >> 1; }
    else             { role = 1; sub = FB + (bid - PAIR2); }
    if (role == 0) {
        fill_body(sub, tid, src, dst, slot, degS, rpnd, nrm, csrw);
    } else {
        int rel = sub / NPB, rowblk = sub - rel * NPB;
        gemm_body<128>(Xh, Xl, w1h, w1l, Y, 512, rowblk, rel);
    }
}

// standalone GEMM: blockIdx.y = relation
template<int BN>
__global__ __launch_bounds__(256)
void gemm_kernel(const short* __restrict__ Xh, const short* __restrict__ Xl,
                 const short* __restrict__ WhT_, const short* __restrict__ WlT_,
                 short* __restrict__ Y_, int CW)
{
    gemm_body<BN>(Xh, Xl, WhT_, WlT_, Y_, CW, blockIdx.x, blockIdx.y);
}

// standalone fill (path B)
__global__ __launch_bounds__(256)
void fill_csr_kernel(const int* __restrict__ src, const int* __restrict__ dst,
                     const unsigned* __restrict__ slot, const unsigned* __restrict__ degS,
                     const uint2* __restrict__ rpnd, const float* __restrict__ nrm,
                     int2* __restrict__ csrw)
{
    fill_body(blockIdx.x, threadIdx.x, src, dst, slot, degS, rpnd, nrm, csrw);
}

// ---------------- CSR gather over NR relations (Y bf16), 4-edge unrolled ----------------
template<int F, int NR>
__global__ __launch_bounds__(256)
void gather_kernel(const short* __restrict__ Y, const unsigned* __restrict__ rowptr,
                   const int2* __restrict__ csrw, const float* __restrict__ bsum,
                   float* __restrict__ H, short* __restrict__ Xh, short* __restrict__ Xl,
                   int CW, int accumulate, int finalize)
{
    constexpr int VF = F / 64;
    int wid = (blockIdx.x * 256 + threadIdx.x) >> 6;
    int lane = threadIdx.x & 63;
    if (wid >= Nn) return;
    float t0 = 0.f, t1 = 0.f;
    #pragma unroll
    for (int rl = 0; rl < NR; ++rl) {
        const short* yr = Y + rl * F;
        unsigned e  = rowptr[rl * Nn + wid];
        unsigned e1 = rowptr[rl * Nn + wid + 1];
        for (; e + 4 <= e1; e += 4) {
            int2 a0 = csrw[e], a1 = csrw[e + 1], a2 = csrw[e + 2], a3 = csrw[e + 3];
            float w0 = __builtin_bit_cast(float, a0.y);
            float w1 = __builtin_bit_cast(float, a1.y);
            float w2 = __builtin_bit_cast(float, a2.y);
            float w3 = __builtin_bit_cast(float, a3.y);
            if constexpr (VF == 2) {
                unsigned p0 = *reinterpret_cast<const unsigned*>(yr + (size_t)a0.x * CW + lane * 2);
                unsigned p1 = *reinterpret_cast<const unsigned*>(yr + (size_t)a1.x * CW + lane * 2);
                unsigned p2 = *reinterpret_cast<const unsigned*>(yr + (size_t)a2.x * CW + lane * 2);
                unsigned p3 = *reinterpret_cast<const unsigned*>(yr + (size_t)a3.x * CW + lane * 2);
                t0 += w0 * bfbits_lo(p0) + w1 * bfbits_lo(p1) + w2 * bfbits_lo(p2) + w3 * bfbits_lo(p3);
                t1 += w0 * bfbits_hi(p0) + w1 * bfbits_hi(p1) + w2 * bfbits_hi(p2) + w3 * bfbits_hi(p3);
            } else {
                unsigned short v0 = *reinterpret_cast<const unsigned short*>(yr + (size_t)a0.x * CW + lane);
                unsigned short v1 = *reinterpret_cast<const unsigned short*>(yr + (size_t)a1.x * CW + lane);
                unsigned short v2 = *reinterpret_cast<const unsigned short*>(yr + (size_t)a2.x * CW + lane);
                unsigned short v3 = *reinterpret_cast<const unsigned short*>(yr + (size_t)a3.x * CW + lane);
                t0 += w0 * bf2f(v0) + w1 * bf2f(v1) + w2 * bf2f(v2) + w3 * bf2f(v3);
            }
        }
        for (; e < e1; ++e) {
            int2 a = csrw[e];
            float wA = __builtin_bit_cast(float, a.y);
            if constexpr (VF == 2) {
                unsigned pA = *reinterpret_cast<const unsigned*>(yr + (size_t)a.x * CW + lane * 2);
                t0 += wA * bfbits_lo(pA);
                t1 += wA * bfbits_hi(pA);
            } else {
                unsigned short vA = *reinterpret_cast<const unsigned short*>(yr + (size_t)a.x * CW + lane);
                t0 += wA * bf2f(vA);
            }
        }
    }
    float* hp = H + (size_t)wid * F + lane * VF;
    if (accumulate) {
        t0 += hp[0]; if (VF == 2) t1 += hp[1];
    } else {
        t0 += bsum[lane * VF]; if (VF == 2) t1 += bsum[lane * VF + 1];
    }
    if (F == 128 && finalize) {
        t0 = fmaxf(t0, 0.f); t1 = fmaxf(t1, 0.f);
        unsigned short h0 = f2bf(t0), h1 = f2bf(t1);
        short2 hv; hv.x = (short)h0; hv.y = (short)h1;
        short2 lv; lv.x = (short)f2bf(t0 - bf2f(h0)); lv.y = (short)f2bf(t1 - bf2f(h1));
        *reinterpret_cast<short2*>(Xh + (size_t)wid * F + lane * 2) = hv;
        *reinterpret_cast<short2*>(Xl + (size_t)wid * F + lane * 2) = lv;
    } else {
        if constexpr (VF == 2) *reinterpret_cast<float2*>(hp) = make_float2(t0, t1);
        else hp[0] = t0;
    }
}

extern "C" void kernel_launch(void* const* d_in, const int* in_sizes, int n_in,
                              void* d_out, int out_size, void* d_ws, size_t ws_size,
                              hipStream_t stream)
{
    const float* x  = (const float*)d_in[0];
    const int* esrc = (const int*)d_in[1];
    const int* edst = (const int*)d_in[2];
    const float* W1 = (const float*)d_in[3];
    const float* b1 = (const float*)d_in[4];
    const float* W2 = (const float*)d_in[5];
    const float* b2 = (const float*)d_in[6];
    float* out = (float*)d_out;

    // ---- workspace layout ----
    char* ws = (char*)d_ws;
    size_t off = 0;
    auto alloc = [&](size_t bytes) { char* p = ws + off; off += (bytes + 255) & ~(size_t)255; return p; };
    unsigned* degS    = (unsigned*)alloc((size_t)NXCD * TOT * 4);   // 12.8MB packed
    unsigned* dsum    = (unsigned*)alloc((size_t)TOT * 4);
    float*    nrm     = (float*)   alloc((size_t)TOT * 4);          // nsrc
    uint2*    rpnd    = (uint2*)   alloc((size_t)TOT * 8);          // {rowptr, ndst}
    unsigned* rowptr  = (unsigned*)alloc((size_t)(TOT + 1) * 4);
    unsigned* partial = (unsigned*)alloc((size_t)NB1 * 4);
    unsigned* slot    = (unsigned*)alloc((size_t)RE * 4);
    float*    bs1     = (float*)   alloc(128 * 4);
    float*    bs2     = (float*)   alloc(64 * 4);
    short*    w1h     = (short*)   alloc((size_t)4 * 128 * 128 * 2);
    short*    w1l     = (short*)   alloc((size_t)4 * 128 * 128 * 2);
    short*    w2h     = (short*)   alloc((size_t)4 * 64 * 128 * 2);
    short*    w2l     = (short*)   alloc((size_t)4 * 64 * 128 * 2);
    int2*     csrw    = (int2*)    alloc((size_t)RE * 8);
    short*    xh      = (short*)   alloc((size_t)NP * 128 * 2);
    short*    xl      = (short*)   alloc((size_t)NP * 128 * 2);

    size_t yslot = (size_t)NP * 128 * 2;          // 25.6MB (bf16, 128 cols)
    bool pathA = (ws_size >= off + 4 * yslot + 4096);
    float* h = nullptr;
    short* Y;
    if (pathA) {
        Y = (short*)alloc(4 * yslot);
    } else {
        h = (float*)alloc((size_t)NP * 128 * 4);
        Y = (short*)alloc(yslot);
    }

    // ---- phase 1: fused prep (count || convx || convw || bsum) ----
    hipMemsetAsync(degS, 0, (size_t)NXCD * TOT * 4, stream);
    prep_kernel<<<PREP_GRID, 256, 0, stream>>>(
        esrc, edst, degS, slot, x, xh, xl, W1, W2,
        w1h, w1l, w2h, w2l, b1, b2, bs1, bs2);

    // ---- phase 2: norms (+shard prefix) + scan ----
    norms_kernel<<<(TOT + 255) / 256, 256, 0, stream>>>(degS, nrm, rpnd, dsum);
    scan1_kernel<<<NB1, 256, 0, stream>>>(dsum, partial);
    scan2_kernel<<<1, NB1, 0, stream>>>(partial, rowptr);
    scan3_kernel<<<NB1, 256, 0, stream>>>(dsum, partial, rowptr, rpnd);

    const int ggrid = (Nn * 64 + 255) / 256;      // one wave per dst node

    if (pathA) {
        // ---- phase 3: fill_csr || gemm128 (4 rel) fused ----
        fill_gemm_kernel<<<FG_GRID, 256, 0, stream>>>(
            esrc, edst, slot, degS, rpnd, nrm, csrw, xh, xl, w1h, w1l, Y);
        // ---- phase 4: layer-1 gather (finalize: bias+ReLU+split into xh/xl) ----
        gather_kernel<128, 4><<<ggrid, 256, 0, stream>>>(
            Y, rowptr, csrw, bs1, out /*unused*/, xh, xl, 512, 0, 1);
        // ---- phase 5: layer-2 GEMM + gather ----
        gemm_kernel<64><<<dim3(NPB, 4), 256, 0, stream>>>(xh, xl, w2h, w2l, Y, 256);
        gather_kernel<64, 4><<<ggrid, 256, 0, stream>>>(
            Y, rowptr, csrw, bs2, out, nullptr, nullptr, 256, 0, 0);
    } else {
        fill_csr_kernel<<<FB, 256, 0, stream>>>(esrc, edst, slot, degS, rpnd, nrm, csrw);
        for (int r = 0; r < Rr; ++r) {
            gemm_kernel<128><<<dim3(NPB, 1), 256, 0, stream>>>(
                xh, xl, w1h + (size_t)r * 128 * 128, w1l + (size_t)r * 128 * 128, Y, 128);
            gather_kernel<128, 1><<<ggrid, 256, 0, stream>>>(
                Y, rowptr + (size_t)r * Nn, csrw, bs1, h, xh, xl, 128, r > 0, r == Rr - 1);
        }
        for (int r = 0; r < Rr; ++r) {
            gemm_kernel<64><<<dim3(NPB, 1), 256, 0, stream>>>(
                xh, xl, w2h + (size_t)r * 64 * 128, w2l + (size_t)r * 64 * 128, Y, 64);
            gather_kernel<64, 1><<<ggrid, 256, 0, stream>>>(
                Y, rowptr + (size_t)r * Nn, csrw, bs2, out, nullptr, nullptr, 64, r > 0, 0);
        }
    }
}

// Round 8
// 547.245 us; speedup vs baseline: 1.1341x; 1.1341x over previous
//
#include <hip/hip_runtime.h>

// RGCN: 2-layer, R=4, N=100000, E=500000/rel, 128->128->64.
// Round 8: revert XCD sharding (null). Phase-1 mega-kernel hides the whole
// layer-1 4-relation MFMA GEMM (inline f32->bf16 hi/lo A-conversion) under
// the atomic-bound degree count. CSR via slot-returning dst atomic.

constexpr int Nn  = 100000;
constexpr int Rr  = 4;
constexpr int Ee  = 500000;
constexpr int RE  = Rr * Ee;
constexpr int TOT = Rr * Nn;
constexpr int NP  = 100096;            // Nn padded to 128 rows
constexpr int NPB = NP / 128;          // 782 row-blocks
constexpr int NB1 = 1024;
constexpr int CH  = (TOT + NB1 - 1) / NB1;

// phase-1 grid decode: count || gemm1 || bsum
constexpr int CB    = (RE + 255) / 256;             // 7813 count blocks
constexpr int GB1   = 4 * NPB;                      // 3128 gemm blocks
constexpr int PAIR1 = 2 * GB1;                      // interleaved region
constexpr int P1_GRID = PAIR1 + (CB - GB1) + 1;

constexpr int FB = (RE / 4 + 255) / 256;            // fill blocks

typedef short bf16x8 __attribute__((ext_vector_type(8)));
typedef float f32x4  __attribute__((ext_vector_type(4)));

__device__ __forceinline__ unsigned short f2bf(float f) {
    unsigned u = __builtin_bit_cast(unsigned, f);
    u = u + 0x7FFFu + ((u >> 16) & 1u);          // round-to-nearest-even
    return (unsigned short)(u >> 16);
}
__device__ __forceinline__ float bf2f(unsigned short h) {
    unsigned u = ((unsigned)h) << 16;
    return __builtin_bit_cast(float, u);
}
__device__ __forceinline__ float bfbits_lo(unsigned p) {
    return __builtin_bit_cast(float, p << 16);
}
__device__ __forceinline__ float bfbits_hi(unsigned p) {
    return __builtin_bit_cast(float, p & 0xFFFF0000u);
}

// ---------------- role bodies ----------------
// deg: [2][TOT]; slot[e] = rank of edge within its (r,dst) segment.
__device__ __forceinline__ void count_body(int sub, int tid,
    const int* __restrict__ src, const int* __restrict__ dst,
    unsigned* __restrict__ deg, unsigned* __restrict__ slot)
{
    int e = sub * 256 + tid;
    if (e >= RE) return;
    int r = (unsigned)e / (unsigned)Ee;
    int base = r * Nn;
    atomicAdd(&deg[base + src[e]], 1u);                     // fire-and-forget
    slot[e] = atomicAdd(&deg[TOT + base + dst[e]], 1u);     // rank in segment
}

__device__ __forceinline__ void bsum_body(int tid,
    const float* __restrict__ b1, const float* __restrict__ b2,
    float* __restrict__ bs1, float* __restrict__ bs2)
{
    if (tid < 128) bs1[tid] = b1[tid] + b1[128 + tid] + b1[256 + tid] + b1[384 + tid];
    if (tid < 64)  bs2[tid] = b2[tid] + b2[64 + tid] + b2[128 + tid] + b2[192 + tid];
}

// ---------------- GEMM body (MFMA, bf16 hi/lo split, bf16 out) ----------------
// CONVA: stage A directly from f32 X with inline hi/lo split (layer 1).
template<int BN, bool CONVA>
__device__ __forceinline__ void gemm_body(
    const short* __restrict__ Xh, const short* __restrict__ Xl,
    const float* __restrict__ Xf,
    const short* __restrict__ WhT_, const short* __restrict__ WlT_,
    short* __restrict__ Y_, int CW, int rowblk, int rel)
{
    constexpr int BM = 128, BKp = 40;            // 32 k + 8 pad
    constexpr int MFR = (BN == 128) ? 4 : 2;
    constexpr int NFR = 4;
    const short* WhT = WhT_ + (size_t)rel * (BN * 128);
    const short* WlT = WlT_ + (size_t)rel * (BN * 128);
    short* Y = Y_ + (size_t)rel * BN;

    __shared__ __align__(16) short Ah[BM * BKp], Al[BM * BKp];
    __shared__ __align__(16) short Bh[BN * BKp], Bl[BN * BKp];

    const int tid = threadIdx.x;
    const int lane = tid & 63, wid = tid >> 6;
    const int lr = lane & 15, lg = lane >> 4;
    const int wm0 = (BN == 128) ? (wid >> 1) * 64 : wid * 32;
    const int wn0 = (BN == 128) ? (wid & 1) * 64 : 0;
    const int row0 = rowblk * BM;

    f32x4 acc[MFR][NFR];
    #pragma unroll
    for (int m = 0; m < MFR; ++m)
        #pragma unroll
        for (int n = 0; n < NFR; ++n)
            #pragma unroll
            for (int j = 0; j < 4; ++j) acc[m][n][j] = 0.f;

    const int sr = tid >> 1;
    const int sko = (tid & 1) * 16;

    for (int ks = 0; ks < 4; ++ks) {
        if constexpr (CONVA) {
            // stage A from f32 x, converting to hi/lo bf16 on the fly
            int grow = row0 + sr;
            float v[16];
            if (grow < Nn) {
                const float* xp = Xf + (size_t)grow * 128 + ks * 32 + sko;
                float4 a0 = *reinterpret_cast<const float4*>(xp);
                float4 a1 = *reinterpret_cast<const float4*>(xp + 4);
                float4 a2 = *reinterpret_cast<const float4*>(xp + 8);
                float4 a3 = *reinterpret_cast<const float4*>(xp + 12);
                v[0]=a0.x; v[1]=a0.y; v[2]=a0.z; v[3]=a0.w;
                v[4]=a1.x; v[5]=a1.y; v[6]=a1.z; v[7]=a1.w;
                v[8]=a2.x; v[9]=a2.y; v[10]=a2.z; v[11]=a2.w;
                v[12]=a3.x; v[13]=a3.y; v[14]=a3.z; v[15]=a3.w;
            } else {
                #pragma unroll
                for (int i = 0; i < 16; ++i) v[i] = 0.f;
            }
            bf16x8 h0, h1, l0, l1;
            #pragma unroll
            for (int i = 0; i < 8; ++i) {
                unsigned short h = f2bf(v[i]);
                h0[i] = (short)h; l0[i] = (short)f2bf(v[i] - bf2f(h));
                unsigned short g = f2bf(v[8 + i]);
                h1[i] = (short)g; l1[i] = (short)f2bf(v[8 + i] - bf2f(g));
            }
            *reinterpret_cast<bf16x8*>(&Ah[sr * BKp + sko])     = h0;
            *reinterpret_cast<bf16x8*>(&Ah[sr * BKp + sko + 8]) = h1;
            *reinterpret_cast<bf16x8*>(&Al[sr * BKp + sko])     = l0;
            *reinterpret_cast<bf16x8*>(&Al[sr * BKp + sko + 8]) = l1;
        } else {
            size_t ga = (size_t)(row0 + sr) * 128 + ks * 32 + sko;
            *reinterpret_cast<bf16x8*>(&Ah[sr * BKp + sko])     = *reinterpret_cast<const bf16x8*>(&Xh[ga]);
            *reinterpret_cast<bf16x8*>(&Ah[sr * BKp + sko + 8]) = *reinterpret_cast<const bf16x8*>(&Xh[ga + 8]);
            *reinterpret_cast<bf16x8*>(&Al[sr * BKp + sko])     = *reinterpret_cast<const bf16x8*>(&Xl[ga]);
            *reinterpret_cast<bf16x8*>(&Al[sr * BKp + sko + 8]) = *reinterpret_cast<const bf16x8*>(&Xl[ga + 8]);
        }
        if (BN == 128 || tid < 128) {
            size_t gb = (size_t)sr * 128 + ks * 32 + sko;
            *reinterpret_cast<bf16x8*>(&Bh[sr * BKp + sko])     = *reinterpret_cast<const bf16x8*>(&WhT[gb]);
            *reinterpret_cast<bf16x8*>(&Bh[sr * BKp + sko + 8]) = *reinterpret_cast<const bf16x8*>(&WhT[gb + 8]);
            *reinterpret_cast<bf16x8*>(&Bl[sr * BKp + sko])     = *reinterpret_cast<const bf16x8*>(&WlT[gb]);
            *reinterpret_cast<bf16x8*>(&Bl[sr * BKp + sko + 8]) = *reinterpret_cast<const bf16x8*>(&WlT[gb + 8]);
        }
        __syncthreads();

        bf16x8 bh[NFR], bl[NFR];
        #pragma unroll
        for (int n = 0; n < NFR; ++n) {
            bh[n] = *reinterpret_cast<const bf16x8*>(&Bh[(wn0 + n * 16 + lr) * BKp + lg * 8]);
            bl[n] = *reinterpret_cast<const bf16x8*>(&Bl[(wn0 + n * 16 + lr) * BKp + lg * 8]);
        }
        #pragma unroll
        for (int m = 0; m < MFR; ++m) {
            bf16x8 ah = *reinterpret_cast<const bf16x8*>(&Ah[(wm0 + m * 16 + lr) * BKp + lg * 8]);
            bf16x8 al = *reinterpret_cast<const bf16x8*>(&Al[(wm0 + m * 16 + lr) * BKp + lg * 8]);
            #pragma unroll
            for (int n = 0; n < NFR; ++n) {
                acc[m][n] = __builtin_amdgcn_mfma_f32_16x16x32_bf16(ah, bh[n], acc[m][n], 0, 0, 0);
                acc[m][n] = __builtin_amdgcn_mfma_f32_16x16x32_bf16(ah, bl[n], acc[m][n], 0, 0, 0);
                acc[m][n] = __builtin_amdgcn_mfma_f32_16x16x32_bf16(al, bh[n], acc[m][n], 0, 0, 0);
            }
        }
        __syncthreads();
    }

    // C/D layout: col=lane&15, row=(lane>>4)*4+j  [m89]
    #pragma unroll
    for (int m = 0; m < MFR; ++m)
        #pragma unroll
        for (int n = 0; n < NFR; ++n) {
            int col = wn0 + n * 16 + lr;
            int rb = row0 + wm0 + m * 16 + lg * 4;
            #pragma unroll
            for (int j = 0; j < 4; ++j)
                Y[(size_t)(rb + j) * CW + col] = (short)f2bf(acc[m][n][j]);
        }
}

// ---------------- phase 1: count || gemm1(4 rel, inline conv) || bsum ----------------
__global__ __launch_bounds__(256)
void phase1_kernel(const int* __restrict__ src, const int* __restrict__ dst,
                   unsigned* __restrict__ deg, unsigned* __restrict__ slot,
                   const float* __restrict__ X,
                   const short* __restrict__ w1h, const short* __restrict__ w1l,
                   short* __restrict__ Y,
                   const float* __restrict__ b1, const float* __restrict__ b2,
                   float* __restrict__ bs1, float* __restrict__ bs2)
{
    int bid = blockIdx.x, tid = threadIdx.x;
    if (bid < PAIR1) {
        int sub = bid >> 1;
        if (bid & 1) {
            int rel = sub & 3, rowblk = sub >> 2;
            gemm_body<128, true>(nullptr, nullptr, X, w1h, w1l, Y, 512, rowblk, rel);
        } else {
            count_body(sub, tid, src, dst, deg, slot);
        }
    } else {
        int t = bid - PAIR1;
        if (t < CB - GB1) count_body(GB1 + t, tid, src, dst, deg, slot);
        else              bsum_body(tid, b1, b2, bs1, bs2);
    }
}

// standalone count (path B)
__global__ __launch_bounds__(256)
void count_kernel(const int* __restrict__ src, const int* __restrict__ dst,
                  unsigned* __restrict__ deg, unsigned* __restrict__ slot)
{
    count_body(blockIdx.x, threadIdx.x, src, dst, deg, slot);
    if (blockIdx.x == 0) { /* nothing */ }
}

__global__ void bsum_kernel(const float* __restrict__ b1, const float* __restrict__ b2,
                            float* __restrict__ bs1, float* __restrict__ bs2)
{
    bsum_body(threadIdx.x, b1, b2, bs1, bs2);
}

// norms; stash ndst bits into packed rpnd
__global__ __launch_bounds__(256)
void norms_kernel(const unsigned* __restrict__ deg, float* __restrict__ nrm,
                  uint2* __restrict__ rpnd)
{
    int gid = blockIdx.x * 256 + threadIdx.x;
    if (gid >= TOT) return;
    unsigned s = deg[gid], d = deg[TOT + gid];
    nrm[gid] = rsqrtf((float)(s > 0u ? s : 1u));
    rpnd[gid].y = __builtin_bit_cast(unsigned, rsqrtf((float)(d > 0u ? d : 1u)));
}

__global__ __launch_bounds__(256)
void scan1_kernel(const unsigned* __restrict__ deg, unsigned* __restrict__ partial)
{
    __shared__ unsigned s[256];
    int b = blockIdx.x, t = threadIdx.x;
    int start = b * CH;
    int n = TOT - start; if (n > CH) n = CH;
    unsigned sum = 0;
    for (int i = t; i < n; i += 256) sum += deg[TOT + start + i];
    s[t] = sum; __syncthreads();
    for (int d = 128; d > 0; d >>= 1) {
        if (t < d) s[t] += s[t + d];
        __syncthreads();
    }
    if (t == 0) partial[b] = s[0];
}

__global__ __launch_bounds__(1024)
void scan2_kernel(unsigned* __restrict__ partial, unsigned* __restrict__ rowptr)
{
    __shared__ unsigned s[NB1];
    int t = threadIdx.x;
    unsigned orig = partial[t];
    s[t] = orig; __syncthreads();
    for (int d = 1; d < NB1; d <<= 1) {
        unsigned v = (t >= d) ? s[t - d] : 0u;
        __syncthreads();
        s[t] += v;
        __syncthreads();
    }
    partial[t] = s[t] - orig;
    if (t == 0) rowptr[TOT] = (unsigned)RE;
}

__global__ __launch_bounds__(256)
void scan3_kernel(const unsigned* __restrict__ deg, const unsigned* __restrict__ base,
                  unsigned* __restrict__ rowptr, uint2* __restrict__ rpnd)
{
    __shared__ unsigned s[CH];
    int b = blockIdx.x, t = threadIdx.x;
    int start = b * CH;
    int n = TOT - start; if (n > CH) n = CH;
    if (n <= 0) return;
    for (int i = t; i < n; i += 256) s[i] = deg[TOT + start + i];
    __syncthreads();
    if (t == 0) {
        unsigned run = base[b];
        for (int i = 0; i < n; ++i) { unsigned v = s[i]; s[i] = run; run += v; }
    }
    __syncthreads();
    for (int i = t; i < n; i += 256) {
        unsigned v = s[i];
        rowptr[start + i] = v;
        rpnd[start + i].x = v;
    }
}

// atomic-free CSR fill: pos = rowptr + slot (4 edges/thread)
__global__ __launch_bounds__(256)
void fill_csr_kernel(const int* __restrict__ src, const int* __restrict__ dst,
                     const unsigned* __restrict__ slot, const uint2* __restrict__ rpnd,
                     const float* __restrict__ nrm, int2* __restrict__ csrw)
{
    int e0 = (blockIdx.x * 256 + threadIdx.x) * 4;
    if (e0 >= RE) return;
    int r = (unsigned)e0 / (unsigned)Ee;
    int base = r * Nn;
    int4 s4 = *reinterpret_cast<const int4*>(src + e0);
    int4 d4 = *reinterpret_cast<const int4*>(dst + e0);
    uint4 sl = *reinterpret_cast<const uint4*>(slot + e0);
    #pragma unroll
    for (int i = 0; i < 4; ++i) {
        int s = (i == 0) ? s4.x : (i == 1) ? s4.y : (i == 2) ? s4.z : s4.w;
        int d = (i == 0) ? d4.x : (i == 1) ? d4.y : (i == 2) ? d4.z : d4.w;
        unsigned k = (i == 0) ? sl.x : (i == 1) ? sl.y : (i == 2) ? sl.z : sl.w;
        uint2 rn = rpnd[base + d];
        float w = nrm[base + s] * __builtin_bit_cast(float, rn.y);
        int2 v; v.x = s; v.y = __builtin_bit_cast(int, w);
        csrw[rn.x + k] = v;
    }
}

// convert W1/W2 to transposed hi/lo bf16
__global__ __launch_bounds__(256)
void convw_kernel(const float* __restrict__ W1, const float* __restrict__ W2,
                  short* __restrict__ w1h, short* __restrict__ w1l,
                  short* __restrict__ w2h, short* __restrict__ w2l)
{
    int gid = blockIdx.x * 256 + threadIdx.x;
    if (gid < 4 * 128 * 128) {
        int r = gid >> 14, rem = gid & 16383, n = rem >> 7, k = rem & 127;
        float v = W1[(r << 14) + k * 128 + n];
        unsigned short h = f2bf(v);
        unsigned short l = f2bf(v - bf2f(h));
        w1h[(r << 14) + n * 128 + k] = (short)h;
        w1l[(r << 14) + n * 128 + k] = (short)l;
    } else {
        int g2 = gid - 65536;
        if (g2 >= 4 * 64 * 128) return;
        int r = g2 >> 13, rem = g2 & 8191, n = rem >> 7, k = rem & 127;
        float v = W2[(r << 13) + k * 64 + n];
        unsigned short h = f2bf(v);
        unsigned short l = f2bf(v - bf2f(h));
        w2h[(r << 13) + n * 128 + k] = (short)h;
        w2l[(r << 13) + n * 128 + k] = (short)l;
    }
}

// standalone GEMM: blockIdx.y = relation
template<int BN, bool CONVA>
__global__ __launch_bounds__(256)
void gemm_kernel(const short* __restrict__ Xh, const short* __restrict__ Xl,
                 const float* __restrict__ Xf,
                 const short* __restrict__ WhT_, const short* __restrict__ WlT_,
                 short* __restrict__ Y_, int CW)
{
    gemm_body<BN, CONVA>(Xh, Xl, Xf, WhT_, WlT_, Y_, CW, blockIdx.x, blockIdx.y);
}

// ---------------- CSR gather over NR relations (Y bf16), 4-edge unrolled ----------------
template<int F, int NR>
__global__ __launch_bounds__(256)
void gather_kernel(const short* __restrict__ Y, const unsigned* __restrict__ rowptr,
                   const int2* __restrict__ csrw, const float* __restrict__ bsum,
                   float* __restrict__ H, short* __restrict__ Xh, short* __restrict__ Xl,
                   int CW, int accumulate, int finalize)
{
    constexpr int VF = F / 64;
    int wid = (blockIdx.x * 256 + threadIdx.x) >> 6;
    int lane = threadIdx.x & 63;
    if (wid >= Nn) return;
    float t0 = 0.f, t1 = 0.f;
    #pragma unroll
    for (int rl = 0; rl < NR; ++rl) {
        const short* yr = Y + rl * F;
        unsigned e  = rowptr[rl * Nn + wid];
        unsigned e1 = rowptr[rl * Nn + wid + 1];
        for (; e + 4 <= e1; e += 4) {
            int2 a0 = csrw[e], a1 = csrw[e + 1], a2 = csrw[e + 2], a3 = csrw[e + 3];
            float w0 = __builtin_bit_cast(float, a0.y);
            float w1 = __builtin_bit_cast(float, a1.y);
            float w2 = __builtin_bit_cast(float, a2.y);
            float w3 = __builtin_bit_cast(float, a3.y);
            if constexpr (VF == 2) {
                unsigned p0 = *reinterpret_cast<const unsigned*>(yr + (size_t)a0.x * CW + lane * 2);
                unsigned p1 = *reinterpret_cast<const unsigned*>(yr + (size_t)a1.x * CW + lane * 2);
                unsigned p2 = *reinterpret_cast<const unsigned*>(yr + (size_t)a2.x * CW + lane * 2);
                unsigned p3 = *reinterpret_cast<const unsigned*>(yr + (size_t)a3.x * CW + lane * 2);
                t0 += w0 * bfbits_lo(p0) + w1 * bfbits_lo(p1) + w2 * bfbits_lo(p2) + w3 * bfbits_lo(p3);
                t1 += w0 * bfbits_hi(p0) + w1 * bfbits_hi(p1) + w2 * bfbits_hi(p2) + w3 * bfbits_hi(p3);
            } else {
                unsigned short v0 = *reinterpret_cast<const unsigned short*>(yr + (size_t)a0.x * CW + lane);
                unsigned short v1 = *reinterpret_cast<const unsigned short*>(yr + (size_t)a1.x * CW + lane);
                unsigned short v2 = *reinterpret_cast<const unsigned short*>(yr + (size_t)a2.x * CW + lane);
                unsigned short v3 = *reinterpret_cast<const unsigned short*>(yr + (size_t)a3.x * CW + lane);
                t0 += w0 * bf2f(v0) + w1 * bf2f(v1) + w2 * bf2f(v2) + w3 * bf2f(v3);
            }
        }
        for (; e < e1; ++e) {
            int2 a = csrw[e];
            float wA = __builtin_bit_cast(float, a.y);
            if constexpr (VF == 2) {
                unsigned pA = *reinterpret_cast<const unsigned*>(yr + (size_t)a.x * CW + lane * 2);
                t0 += wA * bfbits_lo(pA);
                t1 += wA * bfbits_hi(pA);
            } else {
                unsigned short vA = *reinterpret_cast<const unsigned short*>(yr + (size_t)a.x * CW + lane);
                t0 += wA * bf2f(vA);
            }
        }
    }
    float* hp = H + (size_t)wid * F + lane * VF;
    if (accumulate) {
        t0 += hp[0]; if (VF == 2) t1 += hp[1];
    } else {
        t0 += bsum[lane * VF]; if (VF == 2) t1 += bsum[lane * VF + 1];
    }
    if (F == 128 && finalize) {
        t0 = fmaxf(t0, 0.f); t1 = fmaxf(t1, 0.f);
        unsigned short h0 = f2bf(t0), h1 = f2bf(t1);
        short2 hv; hv.x = (short)h0; hv.y = (short)h1;
        short2 lv; lv.x = (short)f2bf(t0 - bf2f(h0)); lv.y = (short)f2bf(t1 - bf2f(h1));
        *reinterpret_cast<short2*>(Xh + (size_t)wid * F + lane * 2) = hv;
        *reinterpret_cast<short2*>(Xl + (size_t)wid * F + lane * 2) = lv;
    } else {
        if constexpr (VF == 2) *reinterpret_cast<float2*>(hp) = make_float2(t0, t1);
        else hp[0] = t0;
    }
}

extern "C" void kernel_launch(void* const* d_in, const int* in_sizes, int n_in,
                              void* d_out, int out_size, void* d_ws, size_t ws_size,
                              hipStream_t stream)
{
    const float* x  = (const float*)d_in[0];
    const int* esrc = (const int*)d_in[1];
    const int* edst = (const int*)d_in[2];
    const float* W1 = (const float*)d_in[3];
    const float* b1 = (const float*)d_in[4];
    const float* W2 = (const float*)d_in[5];
    const float* b2 = (const float*)d_in[6];
    float* out = (float*)d_out;

    // ---- workspace layout ----
    char* ws = (char*)d_ws;
    size_t off = 0;
    auto alloc = [&](size_t bytes) { char* p = ws + off; off += (bytes + 255) & ~(size_t)255; return p; };
    unsigned* deg     = (unsigned*)alloc((size_t)2 * TOT * 4);
    float*    nrm     = (float*)   alloc((size_t)TOT * 4);          // nsrc
    uint2*    rpnd    = (uint2*)   alloc((size_t)TOT * 8);          // {rowptr, ndst}
    unsigned* rowptr  = (unsigned*)alloc((size_t)(TOT + 1) * 4);
    unsigned* partial = (unsigned*)alloc((size_t)NB1 * 4);
    unsigned* slot    = (unsigned*)alloc((size_t)RE * 4);
    float*    bs1     = (float*)   alloc(128 * 4);
    float*    bs2     = (float*)   alloc(64 * 4);
    short*    w1h     = (short*)   alloc((size_t)4 * 128 * 128 * 2);
    short*    w1l     = (short*)   alloc((size_t)4 * 128 * 128 * 2);
    short*    w2h     = (short*)   alloc((size_t)4 * 64 * 128 * 2);
    short*    w2l     = (short*)   alloc((size_t)4 * 64 * 128 * 2);
    int2*     csrw    = (int2*)    alloc((size_t)RE * 8);
    short*    xh      = (short*)   alloc((size_t)NP * 128 * 2);
    short*    xl      = (short*)   alloc((size_t)NP * 128 * 2);

    size_t yslot = (size_t)NP * 128 * 2;          // 25.6MB (bf16, 128 cols)
    bool pathA = (ws_size >= off + 4 * yslot + 4096);
    float* h = nullptr;
    short* Y;
    if (pathA) {
        Y = (short*)alloc(4 * yslot);
    } else {
        h = (float*)alloc((size_t)NP * 128 * 4);
        Y = (short*)alloc(yslot);
    }

    const int ggrid = (Nn * 64 + 255) / 256;      // one wave per dst node

    // ---- phase 0: weight conversion (tiny, independent) ----
    convw_kernel<<<384, 256, 0, stream>>>(W1, W2, w1h, w1l, w2h, w2l);
    hipMemsetAsync(deg, 0, (size_t)2 * TOT * 4, stream);

    if (pathA) {
        // ---- phase 1: count || gemm1(4 rel, inline x conv) || bsum ----
        phase1_kernel<<<P1_GRID, 256, 0, stream>>>(
            esrc, edst, deg, slot, x, w1h, w1l, Y, b1, b2, bs1, bs2);
        // ---- phase 2: norms + scan ----
        norms_kernel<<<(TOT + 255) / 256, 256, 0, stream>>>(deg, nrm, rpnd);
        scan1_kernel<<<NB1, 256, 0, stream>>>(deg, partial);
        scan2_kernel<<<1, NB1, 0, stream>>>(partial, rowptr);
        scan3_kernel<<<NB1, 256, 0, stream>>>(deg, partial, rowptr, rpnd);
        // ---- phase 3: fill ----
        fill_csr_kernel<<<FB, 256, 0, stream>>>(esrc, edst, slot, rpnd, nrm, csrw);
        // ---- phase 4: layer-1 gather (finalize: bias+ReLU+split into xh/xl) ----
        gather_kernel<128, 4><<<ggrid, 256, 0, stream>>>(
            Y, rowptr, csrw, bs1, out /*unused*/, xh, xl, 512, 0, 1);
        // ---- phase 5: layer-2 GEMM + gather ----
        gemm_kernel<64, false><<<dim3(NPB, 4), 256, 0, stream>>>(
            xh, xl, nullptr, w2h, w2l, Y, 256);
        gather_kernel<64, 4><<<ggrid, 256, 0, stream>>>(
            Y, rowptr, csrw, bs2, out, nullptr, nullptr, 256, 0, 0);
    } else {
        count_kernel<<<CB, 256, 0, stream>>>(esrc, edst, deg, slot);
        bsum_kernel<<<1, 128, 0, stream>>>(b1, b2, bs1, bs2);
        norms_kernel<<<(TOT + 255) / 256, 256, 0, stream>>>(deg, nrm, rpnd);
        scan1_kernel<<<NB1, 256, 0, stream>>>(deg, partial);
        scan2_kernel<<<1, NB1, 0, stream>>>(partial, rowptr);
        scan3_kernel<<<NB1, 256, 0, stream>>>(deg, partial, rowptr, rpnd);
        fill_csr_kernel<<<FB, 256, 0, stream>>>(esrc, edst, slot, rpnd, nrm, csrw);
        for (int r = 0; r < Rr; ++r) {
            gemm_kernel<128, true><<<dim3(NPB, 1), 256, 0, stream>>>(
                nullptr, nullptr, x, w1h + (size_t)r * 128 * 128, w1l + (size_t)r * 128 * 128, Y, 128);
            gather_kernel<128, 1><<<ggrid, 256, 0, stream>>>(
                Y, rowptr + (size_t)r * Nn, csrw, bs1, h, xh, xl, 128, r > 0, r == Rr - 1);
        }
        for (int r = 0; r < Rr; ++r) {
            gemm_kernel<64, false><<<dim3(NPB, 1), 256, 0, stream>>>(
                xh, xl, nullptr, w2h + (size_t)r * 64 * 128, w2l + (size_t)r * 64 * 128, Y, 64);
            gather_kernel<64, 1><<<ggrid, 256, 0, stream>>>(
                Y, rowptr + (size_t)r * Nn, csrw, bs2, out, nullptr, nullptr, 64, r > 0, 0);
        }
    }
}